// Round 1
// baseline (87.978 us; speedup 1.0000x reference)
//
#include <hip/hip_runtime.h>
#include <math.h>

#define BB   8
#define IND  128
#define OUTD 128
#define NN   256
#define BN_EPS 1e-5f

// One block per output channel c. threadIdx.x = n (0..255).
// Each block handles all 8 batches -> BatchNorm stats are block-local.
__global__ __launch_bounds__(256) void layer1dpe_fused(
    const float* __restrict__ A,    // [B, IND, NN]
    const float* __restrict__ P1,   // [OUTD, IND]
    const float* __restrict__ P2,   // [OUTD, IND]
    const float* __restrict__ kw,   // [OUTD, IND]
    const float* __restrict__ gamma,// [OUTD]
    const float* __restrict__ beta, // [OUTD]
    float* __restrict__ out)        // [B, OUTD, NN]
{
    const int c = blockIdx.x;
    const int t = threadIdx.x;

    __shared__ float w1[IND], w2[IND], wk[IND];
    if (t < IND) {
        w1[t] = P1[c * IND + t];
        w2[t] = P2[c * IND + t];
        wk[t] = kw[c * IND + t];
    }
    __syncthreads();

    // Projections: a1 = P1[c,:]@A[b,:,t], vv = P2[c,:]@A[b,:,t], kv = k[c,:]@A[b,:,t]
    float a1[BB], vv[BB], kv[BB];
    #pragma unroll
    for (int b = 0; b < BB; ++b) { a1[b] = 0.f; vv[b] = 0.f; kv[b] = 0.f; }

    #pragma unroll 4
    for (int i = 0; i < IND; ++i) {
        const float wa = w1[i];
        const float wb = w2[i];
        const float wc = wk[i];
        #pragma unroll
        for (int b = 0; b < BB; ++b) {
            const float a = A[(b * IND + i) * NN + t];  // coalesced over t
            a1[b] = fmaf(wa, a, a1[b]);
            vv[b] = fmaf(wb, a, vv[b]);
            kv[b] = fmaf(wc, a, kv[b]);
        }
    }

    __shared__ float red[2][4];
    const int wave = t >> 6;
    const int lane = t & 63;

    float pre[BB];
    float bnsum = 0.f, bnsq = 0.f;

    #pragma unroll
    for (int b = 0; b < BB; ++b) {
        // Y[b,c,i] = (sum_j |K_j| V_j) / ||K||  -- independent of i, Q cancels.
        float s2 = kv[b] * kv[b];
        float sv = fabsf(kv[b]) * vv[b];
        #pragma unroll
        for (int off = 32; off >= 1; off >>= 1) {
            s2 += __shfl_xor(s2, off, 64);
            sv += __shfl_xor(sv, off, 64);
        }
        if (lane == 0) { red[0][wave] = s2; red[1][wave] = sv; }
        __syncthreads();
        const float S2 = red[0][0] + red[0][1] + red[0][2] + red[0][3];
        const float SV = red[1][0] + red[1][1] + red[1][2] + red[1][3];
        __syncthreads();  // protect red[] reuse next iteration

        const float y = SV / sqrtf(S2);
        float p = a1[b] + vv[b] + 0.1f * y;
        p = fmaxf(p, 0.f);                 // ReLU
        pre[b] = p;
        bnsum += p;
        bnsq  += p * p;
    }

    // BatchNorm stats over (B, N) = 2048 elems, all local to this block.
    #pragma unroll
    for (int off = 32; off >= 1; off >>= 1) {
        bnsum += __shfl_xor(bnsum, off, 64);
        bnsq  += __shfl_xor(bnsq,  off, 64);
    }
    if (lane == 0) { red[0][wave] = bnsum; red[1][wave] = bnsq; }
    __syncthreads();
    const float tsum = red[0][0] + red[0][1] + red[0][2] + red[0][3];
    const float tsq  = red[1][0] + red[1][1] + red[1][2] + red[1][3];

    const float inv  = 1.f / (float)(BB * NN);
    const float mean = tsum * inv;
    const float var  = tsq * inv - mean * mean;   // biased var (ddof=0), matches jnp.var
    const float scale = gamma[c] * rsqrtf(var + BN_EPS);
    const float shift = beta[c] - mean * scale;

    #pragma unroll
    for (int b = 0; b < BB; ++b) {
        out[(b * OUTD + c) * NN + t] = fmaf(pre[b], scale, shift);
    }
}

extern "C" void kernel_launch(void* const* d_in, const int* in_sizes, int n_in,
                              void* d_out, int out_size, void* d_ws, size_t ws_size,
                              hipStream_t stream) {
    // setup_inputs order: A, P1, P2, q, k, gamma, beta, permutation_size1, BATCH_SIZE
    const float* A     = (const float*)d_in[0];
    const float* P1    = (const float*)d_in[1];
    const float* P2    = (const float*)d_in[2];
    // d_in[3] = q : unused (cancels in Alpha_norm)
    const float* kw    = (const float*)d_in[4];
    const float* gamma = (const float*)d_in[5];
    const float* beta  = (const float*)d_in[6];
    float* out = (float*)d_out;

    layer1dpe_fused<<<OUTD, 256, 0, stream>>>(A, P1, P2, kw, gamma, beta, out);
}